// Round 1
// baseline (1457.926 us; speedup 1.0000x reference)
//
#include <hip/hip_runtime.h>
#include <math.h>

#define N_NODES 100000
#define N_EDGES 3200000
#define D_IN    256
#define D_HID   32
#define N_CLS   40

// ---------------- degree / norm precompute ----------------

__global__ void k_init_deg(float* __restrict__ deg) {
    int i = blockIdx.x * 256 + threadIdx.x;
    if (i < N_NODES) deg[i] = 1.0f;   // self-loop weight
}

__global__ void k_accum_deg(const int* __restrict__ col, const float* __restrict__ w,
                            float* __restrict__ deg) {
    int e = blockIdx.x * 256 + threadIdx.x;
    if (e < N_EDGES) atomicAdd(&deg[col[e]], w[e]);
}

__global__ void k_rsqrt(float* __restrict__ deg) {
    int i = blockIdx.x * 256 + threadIdx.x;
    if (i < N_NODES) {
        float d = deg[i];
        deg[i] = d > 0.f ? rsqrtf(d) : 0.f;
    }
}

__global__ void k_norm(const int* __restrict__ row, const int* __restrict__ col,
                       const float* __restrict__ w, const float* __restrict__ dis,
                       float* __restrict__ nrm) {
    int e = blockIdx.x * 256 + threadIdx.x;
    if (e < N_EDGES) nrm[e] = dis[row[e]] * w[e] * dis[col[e]];
}

// ---------------- GEMM1: g = x @ Wc^T  (100000x256 @ 256x32) ----------------
// 32 nodes per 256-thread block. x tile and W both staged in LDS with
// stride 260 floats (16B aligned rows, conflict-free b128 reads).
// Thread t: node = t>>3, outputs {og, og+8, og+16, og+24} with og = t&7
// -> W rows for one read instruction have distinct bank bases (4*og).

#define LSTRIDE 260

__global__ __launch_bounds__(256) void k_gemm1(const float* __restrict__ x,
                                               const float* __restrict__ Wc,
                                               float* __restrict__ g) {
    __shared__ float xs[32 * LSTRIDE];
    __shared__ float wsl[32 * LSTRIDE];
    const int tid  = threadIdx.x;
    const int base = blockIdx.x * 32;

    // stage x tile: 32 rows x 256 floats = 2048 float4, coalesced
    for (int i = tid; i < 2048; i += 256) {
        int r = i >> 6, j = i & 63;
        float4 v = reinterpret_cast<const float4*>(x)[(size_t)(base + r) * 64 + j];
        *reinterpret_cast<float4*>(&xs[r * LSTRIDE + j * 4]) = v;
    }
    // stage W: 32x256
    for (int i = tid; i < 2048; i += 256) {
        int r = i >> 6, j = i & 63;
        float4 v = reinterpret_cast<const float4*>(Wc)[i];
        *reinterpret_cast<float4*>(&wsl[r * LSTRIDE + j * 4]) = v;
    }
    __syncthreads();

    const int node = tid >> 3;   // 0..31
    const int og   = tid & 7;    // 0..7
    float4 acc = make_float4(0.f, 0.f, 0.f, 0.f);
    const float* xrow = &xs[node * LSTRIDE];
    const float* w0 = &wsl[(og     ) * LSTRIDE];
    const float* w1 = &wsl[(og +  8) * LSTRIDE];
    const float* w2 = &wsl[(og + 16) * LSTRIDE];
    const float* w3 = &wsl[(og + 24) * LSTRIDE];

#pragma unroll 4
    for (int k = 0; k < 256; k += 4) {
        float4 xv = *reinterpret_cast<const float4*>(&xrow[k]);
        float4 a4 = *reinterpret_cast<const float4*>(&w0[k]);
        float4 b4 = *reinterpret_cast<const float4*>(&w1[k]);
        float4 c4 = *reinterpret_cast<const float4*>(&w2[k]);
        float4 d4 = *reinterpret_cast<const float4*>(&w3[k]);
        acc.x += xv.x * a4.x + xv.y * a4.y + xv.z * a4.z + xv.w * a4.w;
        acc.y += xv.x * b4.x + xv.y * b4.y + xv.z * b4.z + xv.w * b4.w;
        acc.z += xv.x * c4.x + xv.y * c4.y + xv.z * c4.z + xv.w * c4.w;
        acc.w += xv.x * d4.x + xv.y * d4.y + xv.z * d4.z + xv.w * d4.w;
    }
    size_t gb = (size_t)(base + node) * D_HID;
    g[gb + og     ] = acc.x;
    g[gb + og +  8] = acc.y;
    g[gb + og + 16] = acc.z;
    g[gb + og + 24] = acc.w;
}

// ---------------- diffusion hop ----------------

__global__ void k_hop_init(const float* __restrict__ h, const float* __restrict__ dis,
                           float* __restrict__ out) {
    int i = blockIdx.x * 256 + threadIdx.x;   // over N_NODES*32
    if (i < N_NODES * D_HID) {
        float s = dis[i >> 5];
        out[i] = s * s * h[i];   // self-loop: norm = dis*1*dis
    }
}

__global__ __launch_bounds__(256) void k_hop_scatter(const int* __restrict__ row,
                                                     const int* __restrict__ col,
                                                     const float* __restrict__ nrm,
                                                     const float* __restrict__ h,
                                                     float* __restrict__ out) {
    int t = blockIdx.x * 256 + threadIdx.x;
    int e = t >> 5;          // 8 edges per block, 32 lanes per edge
    int l = t & 31;
    if (e < N_EDGES) {
        int r = row[e];
        int c = col[e];
        float nv = nrm[e];
        float v = h[(size_t)r * D_HID + l];
        atomicAdd(&out[(size_t)c * D_HID + l], nv * v);
    }
}

// ---------------- epilogue: bias + ELU + FC + log_softmax ----------------

__global__ __launch_bounds__(256) void k_final(const float* __restrict__ h,
                                               const float* __restrict__ bc,
                                               const float* __restrict__ Wfc,
                                               const float* __restrict__ bf,
                                               float* __restrict__ out) {
    __shared__ float wf[N_CLS * D_HID];
    __shared__ float bcs[D_HID];
    __shared__ float bfs[N_CLS];
    const int tid = threadIdx.x;
    for (int i = tid; i < N_CLS * D_HID; i += 256) wf[i] = Wfc[i];
    if (tid < D_HID) bcs[tid] = bc[tid];
    if (tid < N_CLS) bfs[tid] = bf[tid];
    __syncthreads();

    int node = blockIdx.x * 256 + tid;
    if (node >= N_NODES) return;

    float a[D_HID];
    const float4* hp = reinterpret_cast<const float4*>(h + (size_t)node * D_HID);
#pragma unroll
    for (int j = 0; j < 8; ++j) {
        float4 v = hp[j];
        float z0 = v.x + bcs[j * 4 + 0];
        float z1 = v.y + bcs[j * 4 + 1];
        float z2 = v.z + bcs[j * 4 + 2];
        float z3 = v.w + bcs[j * 4 + 3];
        a[j * 4 + 0] = z0 > 0.f ? z0 : expm1f(z0);
        a[j * 4 + 1] = z1 > 0.f ? z1 : expm1f(z1);
        a[j * 4 + 2] = z2 > 0.f ? z2 : expm1f(z2);
        a[j * 4 + 3] = z3 > 0.f ? z3 : expm1f(z3);
    }

    float logits[N_CLS];
    float m = -1e30f;
#pragma unroll
    for (int c = 0; c < N_CLS; ++c) {
        float accv = bfs[c];
        const float* wr = &wf[c * D_HID];
#pragma unroll
        for (int o = 0; o < D_HID; ++o) accv += a[o] * wr[o];
        logits[c] = accv;
        m = fmaxf(m, accv);
    }
    float s = 0.f;
#pragma unroll
    for (int c = 0; c < N_CLS; ++c) s += expf(logits[c] - m);
    float lse = m + logf(s);
    float* op = out + (size_t)node * N_CLS;
#pragma unroll
    for (int c = 0; c < N_CLS; ++c) op[c] = logits[c] - lse;
}

// ---------------- launch ----------------

extern "C" void kernel_launch(void* const* d_in, const int* in_sizes, int n_in,
                              void* d_out, int out_size, void* d_ws, size_t ws_size,
                              hipStream_t stream) {
    const float* x   = (const float*)d_in[0];
    const int*   ei  = (const int*)d_in[1];
    const float* ea  = (const float*)d_in[2];
    const float* Wc  = (const float*)d_in[3];
    const float* bc  = (const float*)d_in[4];
    const float* Wfc = (const float*)d_in[5];
    const float* bf  = (const float*)d_in[6];
    float* out = (float*)d_out;
    float* ws  = (float*)d_ws;

    const int* row = ei;             // edge_index[0]
    const int* col = ei + N_EDGES;   // edge_index[1]

    float* dis  = ws;                        // N_NODES (deg -> dis in place)
    float* nrm  = ws + 131072;               // N_EDGES
    float* bufA = nrm + N_EDGES;             // N_NODES*32
    float* bufB = bufA + (size_t)N_NODES * D_HID;

    const int GN  = (N_NODES + 255) / 256;          // 391
    const int GE  = (N_EDGES + 255) / 256;          // 12500
    const int GH  = (N_NODES * D_HID + 255) / 256;  // 12500
    const int GS  = (N_EDGES * D_HID) / 256;        // 400000

    k_init_deg<<<GN, 256, 0, stream>>>(dis);
    k_accum_deg<<<GE, 256, 0, stream>>>(col, ea, dis);
    k_rsqrt<<<GN, 256, 0, stream>>>(dis);
    k_norm<<<GE, 256, 0, stream>>>(row, col, ea, dis, nrm);

    k_gemm1<<<N_NODES / 32, 256, 0, stream>>>(x, Wc, bufA);

    // hop 1: A -> B
    k_hop_init<<<GH, 256, 0, stream>>>(bufA, dis, bufB);
    k_hop_scatter<<<GS, 256, 0, stream>>>(row, col, nrm, bufA, bufB);
    // hop 2: B -> A
    k_hop_init<<<GH, 256, 0, stream>>>(bufB, dis, bufA);
    k_hop_scatter<<<GS, 256, 0, stream>>>(row, col, nrm, bufB, bufA);
    // hop 3: A -> B
    k_hop_init<<<GH, 256, 0, stream>>>(bufA, dis, bufB);
    k_hop_scatter<<<GS, 256, 0, stream>>>(row, col, nrm, bufA, bufB);

    k_final<<<GN, 256, 0, stream>>>(bufB, bc, Wfc, bf, out);
}

// Round 2
// 958.617 us; speedup vs baseline: 1.5209x; 1.5209x over previous
//
#include <hip/hip_runtime.h>
#include <math.h>

#define N_NODES 100000
#define N_EDGES 3200000
#define D_IN    256
#define D_HID   32
#define N_CLS   40

#define SCAN_BLK 1024
#define N_SCAN_BLKS ((N_NODES + SCAN_BLK - 1) / SCAN_BLK)   // 98

// ---------------- init: deg=1 (self loop), cnt=0 ----------------

__global__ void k_init(float* __restrict__ deg, int* __restrict__ cnt) {
    int i = blockIdx.x * 256 + threadIdx.x;
    if (i < N_NODES) { deg[i] = 1.0f; cnt[i] = 0; }
}

// ---------------- per-edge: weighted degree + in-degree count ----------------

__global__ void k_count(const int* __restrict__ col, const float* __restrict__ w,
                        float* __restrict__ deg, int* __restrict__ cnt) {
    int e = blockIdx.x * 256 + threadIdx.x;
    if (e < N_EDGES) {
        int c = col[e];
        atomicAdd(&deg[c], w[e]);
        atomicAdd(&cnt[c], 1);
    }
}

__global__ void k_rsqrt(float* __restrict__ deg) {
    int i = blockIdx.x * 256 + threadIdx.x;
    if (i < N_NODES) {
        float d = deg[i];
        deg[i] = d > 0.f ? rsqrtf(d) : 0.f;
    }
}

// ---------------- prefix scan: cnt -> start (exclusive, N+1 entries) ----------------

__global__ __launch_bounds__(SCAN_BLK) void k_scan1(const int* __restrict__ cnt,
                                                    int* __restrict__ inc,
                                                    int* __restrict__ part) {
    __shared__ int s[SCAN_BLK];
    int t = threadIdx.x;
    int i = blockIdx.x * SCAN_BLK + t;
    s[t] = (i < N_NODES) ? cnt[i] : 0;
    __syncthreads();
    for (int off = 1; off < SCAN_BLK; off <<= 1) {
        int u = (t >= off) ? s[t - off] : 0;
        __syncthreads();
        s[t] += u;
        __syncthreads();
    }
    if (i < N_NODES) inc[i] = s[t];
    if (t == SCAN_BLK - 1) part[blockIdx.x] = s[t];
}

__global__ __launch_bounds__(128) void k_scan2(const int* __restrict__ part,
                                               int* __restrict__ pexcl) {
    __shared__ int s[128];
    int t = threadIdx.x;
    s[t] = (t < N_SCAN_BLKS) ? part[t] : 0;
    __syncthreads();
    for (int off = 1; off < 128; off <<= 1) {
        int u = (t >= off) ? s[t - off] : 0;
        __syncthreads();
        s[t] += u;
        __syncthreads();
    }
    if (t < N_SCAN_BLKS) pexcl[t] = (t == 0) ? 0 : s[t - 1];
}

__global__ void k_scan3(const int* __restrict__ inc, const int* __restrict__ pexcl,
                        int* __restrict__ start) {
    int i = blockIdx.x * 256 + threadIdx.x;
    if (i < N_NODES) {
        start[i + 1] = inc[i] + pexcl[i >> 10];
        if (i == 0) start[0] = 0;
    }
}

__global__ void k_cursor(const int* __restrict__ start, int* __restrict__ cursor) {
    int i = blockIdx.x * 256 + threadIdx.x;
    if (i < N_NODES) cursor[i] = start[i];
}

// ---------------- CSR fill: packed (src, norm) per edge, bucketed by dst ----------------

__global__ void k_fill(const int* __restrict__ row, const int* __restrict__ col,
                       const float* __restrict__ w, const float* __restrict__ dis,
                       int* __restrict__ cursor, int2* __restrict__ csr) {
    int e = blockIdx.x * 256 + threadIdx.x;
    if (e < N_EDGES) {
        int r = row[e], c = col[e];
        float nv = dis[r] * w[e] * dis[c];
        int p = atomicAdd(&cursor[c], 1);
        csr[p] = make_int2(r, __float_as_int(nv));
    }
}

// ---------------- GEMM1: g = x @ Wc^T  (100000x256 @ 256x32) ----------------

#define LSTRIDE 260

__global__ __launch_bounds__(256) void k_gemm1(const float* __restrict__ x,
                                               const float* __restrict__ Wc,
                                               float* __restrict__ g) {
    __shared__ float xs[32 * LSTRIDE];
    __shared__ float wsl[32 * LSTRIDE];
    const int tid  = threadIdx.x;
    const int base = blockIdx.x * 32;

    for (int i = tid; i < 2048; i += 256) {
        int r = i >> 6, j = i & 63;
        float4 v = reinterpret_cast<const float4*>(x)[(size_t)(base + r) * 64 + j];
        *reinterpret_cast<float4*>(&xs[r * LSTRIDE + j * 4]) = v;
    }
    for (int i = tid; i < 2048; i += 256) {
        int r = i >> 6, j = i & 63;
        float4 v = reinterpret_cast<const float4*>(Wc)[i];
        *reinterpret_cast<float4*>(&wsl[r * LSTRIDE + j * 4]) = v;
    }
    __syncthreads();

    const int node = tid >> 3;
    const int og   = tid & 7;
    float4 acc = make_float4(0.f, 0.f, 0.f, 0.f);
    const float* xrow = &xs[node * LSTRIDE];
    const float* w0 = &wsl[(og     ) * LSTRIDE];
    const float* w1 = &wsl[(og +  8) * LSTRIDE];
    const float* w2 = &wsl[(og + 16) * LSTRIDE];
    const float* w3 = &wsl[(og + 24) * LSTRIDE];

#pragma unroll 4
    for (int k = 0; k < 256; k += 4) {
        float4 xv = *reinterpret_cast<const float4*>(&xrow[k]);
        float4 a4 = *reinterpret_cast<const float4*>(&w0[k]);
        float4 b4 = *reinterpret_cast<const float4*>(&w1[k]);
        float4 c4 = *reinterpret_cast<const float4*>(&w2[k]);
        float4 d4 = *reinterpret_cast<const float4*>(&w3[k]);
        acc.x += xv.x * a4.x + xv.y * a4.y + xv.z * a4.z + xv.w * a4.w;
        acc.y += xv.x * b4.x + xv.y * b4.y + xv.z * b4.z + xv.w * b4.w;
        acc.z += xv.x * c4.x + xv.y * c4.y + xv.z * c4.z + xv.w * c4.w;
        acc.w += xv.x * d4.x + xv.y * d4.y + xv.z * d4.z + xv.w * d4.w;
    }
    size_t gb = (size_t)(base + node) * D_HID;
    g[gb + og     ] = acc.x;
    g[gb + og +  8] = acc.y;
    g[gb + og + 16] = acc.z;
    g[gb + og + 24] = acc.w;
}

// ---------------- pull hop: out[c] = dis[c]^2*h[c] + sum_{e: col=c} nrm_e * h[row_e] ----------------
// One 32-lane group per destination node; lane = feature dim.

__global__ __launch_bounds__(256) void k_pull(const int* __restrict__ start,
                                              const int2* __restrict__ csr,
                                              const float* __restrict__ dis,
                                              const float* __restrict__ h,
                                              float* __restrict__ out) {
    int g    = blockIdx.x * 8 + (threadIdx.x >> 5);
    int lane = threadIdx.x & 31;
    if (g >= N_NODES) return;

    int s = start[g];
    int e = start[g + 1];
    float ds   = dis[g];
    float self = h[(size_t)g * D_HID + lane];
    float acc0 = ds * ds * self;
    float acc1 = 0.f;

    for (int base = s; base < e; base += 32) {
        int idx = base + lane;
        int r = g; float nv = 0.f;            // pad with self row (L1-hot), weight 0
        if (idx < e) {
            int2 p = csr[idx];
            r  = p.x;
            nv = __int_as_float(p.y);
        }
#pragma unroll
        for (int j = 0; j < 32; j += 2) {
            int   r0 = __shfl(r,  j,     32);
            float n0 = __shfl(nv, j,     32);
            int   r1 = __shfl(r,  j + 1, 32);
            float n1 = __shfl(nv, j + 1, 32);
            acc0 += n0 * h[(size_t)r0 * D_HID + lane];
            acc1 += n1 * h[(size_t)r1 * D_HID + lane];
        }
    }
    out[(size_t)g * D_HID + lane] = acc0 + acc1;
}

// ---------------- epilogue: bias + ELU + FC + log_softmax ----------------

__global__ __launch_bounds__(256) void k_final(const float* __restrict__ h,
                                               const float* __restrict__ bc,
                                               const float* __restrict__ Wfc,
                                               const float* __restrict__ bf,
                                               float* __restrict__ out) {
    __shared__ float wf[N_CLS * D_HID];
    __shared__ float bcs[D_HID];
    __shared__ float bfs[N_CLS];
    const int tid = threadIdx.x;
    for (int i = tid; i < N_CLS * D_HID; i += 256) wf[i] = Wfc[i];
    if (tid < D_HID) bcs[tid] = bc[tid];
    if (tid < N_CLS) bfs[tid] = bf[tid];
    __syncthreads();

    int node = blockIdx.x * 256 + tid;
    if (node >= N_NODES) return;

    float a[D_HID];
    const float4* hp = reinterpret_cast<const float4*>(h + (size_t)node * D_HID);
#pragma unroll
    for (int j = 0; j < 8; ++j) {
        float4 v = hp[j];
        float z0 = v.x + bcs[j * 4 + 0];
        float z1 = v.y + bcs[j * 4 + 1];
        float z2 = v.z + bcs[j * 4 + 2];
        float z3 = v.w + bcs[j * 4 + 3];
        a[j * 4 + 0] = z0 > 0.f ? z0 : expm1f(z0);
        a[j * 4 + 1] = z1 > 0.f ? z1 : expm1f(z1);
        a[j * 4 + 2] = z2 > 0.f ? z2 : expm1f(z2);
        a[j * 4 + 3] = z3 > 0.f ? z3 : expm1f(z3);
    }

    float logits[N_CLS];
    float m = -1e30f;
#pragma unroll
    for (int c = 0; c < N_CLS; ++c) {
        float accv = bfs[c];
        const float* wr = &wf[c * D_HID];
#pragma unroll
        for (int o = 0; o < D_HID; ++o) accv += a[o] * wr[o];
        logits[c] = accv;
        m = fmaxf(m, accv);
    }
    float s = 0.f;
#pragma unroll
    for (int c = 0; c < N_CLS; ++c) s += expf(logits[c] - m);
    float lse = m + logf(s);
    float* op = out + (size_t)node * N_CLS;
#pragma unroll
    for (int c = 0; c < N_CLS; ++c) op[c] = logits[c] - lse;
}

// ---------------- launch ----------------

extern "C" void kernel_launch(void* const* d_in, const int* in_sizes, int n_in,
                              void* d_out, int out_size, void* d_ws, size_t ws_size,
                              hipStream_t stream) {
    const float* x   = (const float*)d_in[0];
    const int*   ei  = (const int*)d_in[1];
    const float* ea  = (const float*)d_in[2];
    const float* Wc  = (const float*)d_in[3];
    const float* bc  = (const float*)d_in[4];
    const float* Wfc = (const float*)d_in[5];
    const float* bf  = (const float*)d_in[6];
    float* out = (float*)d_out;
    float* ws  = (float*)d_ws;

    const int* row = ei;             // edge_index[0]
    const int* col = ei + N_EDGES;   // edge_index[1]

    // workspace layout (element offsets, all multiples of 4 -> 16B aligned)
    float* dis    = ws;                                  // [0, 100000)
    int*   cnt    = (int*)(ws + 100000);                 // 100000
    int*   inc    = (int*)(ws + 200000);                 // 100000
    int*   part   = (int*)(ws + 300000);                 // 128
    int*   pexcl  = (int*)(ws + 300128);                 // 128
    int*   startp = (int*)(ws + 300256);                 // 100001
    int*   cursor = (int*)(ws + 400260);                 // 100000
    int2*  csr    = (int2*)(ws + 500260);                // 3.2M int2 = 6.4M elems
    float* bufA   = ws + 6900260;                        // 3.2M
    float* bufB   = ws + 10100260;                       // 3.2M
    // total 13,300,260 floats = 53.2 MB

    const int GN = (N_NODES + 255) / 256;    // 391
    const int GE = (N_EDGES + 255) / 256;    // 12500
    const int GP = (N_NODES + 7) / 8;        // 12500 (pull: 8 nodes/block)

    k_init  <<<GN, 256, 0, stream>>>(dis, cnt);
    k_count <<<GE, 256, 0, stream>>>(col, ea, dis, cnt);
    k_rsqrt <<<GN, 256, 0, stream>>>(dis);

    k_scan1 <<<N_SCAN_BLKS, SCAN_BLK, 0, stream>>>(cnt, inc, part);
    k_scan2 <<<1, 128, 0, stream>>>(part, pexcl);
    k_scan3 <<<GN, 256, 0, stream>>>(inc, pexcl, startp);
    k_cursor<<<GN, 256, 0, stream>>>(startp, cursor);
    k_fill  <<<GE, 256, 0, stream>>>(row, col, ea, dis, cursor, csr);

    k_gemm1 <<<N_NODES / 32, 256, 0, stream>>>(x, Wc, bufA);

    k_pull  <<<GP, 256, 0, stream>>>(startp, csr, dis, bufA, bufB);
    k_pull  <<<GP, 256, 0, stream>>>(startp, csr, dis, bufB, bufA);
    k_pull  <<<GP, 256, 0, stream>>>(startp, csr, dis, bufA, bufB);

    k_final <<<GN, 256, 0, stream>>>(bufB, bc, Wfc, bf, out);
}

// Round 3
// 807.002 us; speedup vs baseline: 1.8066x; 1.1879x over previous
//
#include <hip/hip_runtime.h>
#include <math.h>

#define N_NODES 100000
#define N_EDGES 3200000
#define D_IN    256
#define D_HID   32
#define N_CLS   40

#define SCAN_BLK 1024
#define N_SCAN_BLKS ((N_NODES + SCAN_BLK - 1) / SCAN_BLK)   // 98

typedef unsigned long long u64;
typedef unsigned int u32;

// ---------------- per-edge: packed (count<<42 | fixed-point weight sum) ----------------

__global__ void k_count(const int* __restrict__ col, const float* __restrict__ w,
                        u64* __restrict__ packed) {
    int e = blockIdx.x * 256 + threadIdx.x;
    if (e < N_EDGES) {
        u64 v = (1ULL << 42) | (u64)(w[e] * 4294967296.0f);
        atomicAdd(&packed[col[e]], v);
    }
}

// ---------------- scan pass 1: extract cnt, scan within block; also dis = rsqrt(1+wsum) ----------------

__global__ __launch_bounds__(SCAN_BLK) void k_scan1(const u64* __restrict__ packed,
                                                    float* __restrict__ dis,
                                                    int* __restrict__ inc,
                                                    int* __restrict__ part) {
    __shared__ int s[SCAN_BLK];
    int t = threadIdx.x;
    int i = blockIdx.x * SCAN_BLK + t;
    int c = 0;
    if (i < N_NODES) {
        u64 p = packed[i];
        c = (int)(p >> 42);
        float wsum = (float)(p & ((1ULL << 42) - 1)) * (1.0f / 4294967296.0f);
        dis[i] = rsqrtf(1.0f + wsum);
    }
    s[t] = c;
    __syncthreads();
    for (int off = 1; off < SCAN_BLK; off <<= 1) {
        int u = (t >= off) ? s[t - off] : 0;
        __syncthreads();
        s[t] += u;
        __syncthreads();
    }
    if (i < N_NODES) inc[i] = s[t];
    if (t == SCAN_BLK - 1) part[blockIdx.x] = s[t];
}

__global__ __launch_bounds__(128) void k_scan2(const int* __restrict__ part,
                                               int* __restrict__ pexcl) {
    __shared__ int s[128];
    int t = threadIdx.x;
    s[t] = (t < N_SCAN_BLKS) ? part[t] : 0;
    __syncthreads();
    for (int off = 1; off < 128; off <<= 1) {
        int u = (t >= off) ? s[t - off] : 0;
        __syncthreads();
        s[t] += u;
        __syncthreads();
    }
    if (t < N_SCAN_BLKS) pexcl[t] = (t == 0) ? 0 : s[t - 1];
}

// start[i+1] = scan(cnt)[i]; cursor initialized to start in the same pass
__global__ void k_scan3(const int* __restrict__ inc, const int* __restrict__ pexcl,
                        int* __restrict__ start, int* __restrict__ cursor) {
    int i = blockIdx.x * 256 + threadIdx.x;
    if (i < N_NODES) {
        int v = inc[i] + pexcl[i >> 10];
        start[i + 1] = v;
        if (i + 1 < N_NODES) cursor[i + 1] = v;
        if (i == 0) { start[0] = 0; cursor[0] = 0; }
    }
}

// ---------------- CSR fill: 4B packed (src<<15 | fixed15 norm), bucketed by dst ----------------

__global__ void k_fill(const int* __restrict__ row, const int* __restrict__ col,
                       const float* __restrict__ w, const float* __restrict__ dis,
                       int* __restrict__ cursor, u32* __restrict__ csr) {
    int e = blockIdx.x * 256 + threadIdx.x;
    if (e < N_EDGES) {
        int r = row[e], c = col[e];
        float nv = dis[r] * w[e] * dis[c];          // provably < 0.708
        u32 q = (u32)(nv * 32768.0f + 0.5f);
        q = q > 32767u ? 32767u : q;
        u32 entry = ((u32)r << 15) | q;
        int p = atomicAdd(&cursor[c], 1);
        csr[p] = entry;
    }
}

// ---------------- GEMM1: g = x @ Wc^T  (100000x256 @ 256x32) ----------------

#define LSTRIDE 260

__global__ __launch_bounds__(256) void k_gemm1(const float* __restrict__ x,
                                               const float* __restrict__ Wc,
                                               float* __restrict__ g) {
    __shared__ float xs[32 * LSTRIDE];
    __shared__ float wsl[32 * LSTRIDE];
    const int tid  = threadIdx.x;
    const int base = blockIdx.x * 32;

    for (int i = tid; i < 2048; i += 256) {
        int r = i >> 6, j = i & 63;
        float4 v = reinterpret_cast<const float4*>(x)[(size_t)(base + r) * 64 + j];
        *reinterpret_cast<float4*>(&xs[r * LSTRIDE + j * 4]) = v;
    }
    for (int i = tid; i < 2048; i += 256) {
        int r = i >> 6, j = i & 63;
        float4 v = reinterpret_cast<const float4*>(Wc)[i];
        *reinterpret_cast<float4*>(&wsl[r * LSTRIDE + j * 4]) = v;
    }
    __syncthreads();

    const int node = tid >> 3;
    const int og   = tid & 7;
    float4 acc = make_float4(0.f, 0.f, 0.f, 0.f);
    const float* xrow = &xs[node * LSTRIDE];
    const float* w0 = &wsl[(og     ) * LSTRIDE];
    const float* w1 = &wsl[(og +  8) * LSTRIDE];
    const float* w2 = &wsl[(og + 16) * LSTRIDE];
    const float* w3 = &wsl[(og + 24) * LSTRIDE];

#pragma unroll 4
    for (int k = 0; k < 256; k += 4) {
        float4 xv = *reinterpret_cast<const float4*>(&xrow[k]);
        float4 a4 = *reinterpret_cast<const float4*>(&w0[k]);
        float4 b4 = *reinterpret_cast<const float4*>(&w1[k]);
        float4 c4 = *reinterpret_cast<const float4*>(&w2[k]);
        float4 d4 = *reinterpret_cast<const float4*>(&w3[k]);
        acc.x += xv.x * a4.x + xv.y * a4.y + xv.z * a4.z + xv.w * a4.w;
        acc.y += xv.x * b4.x + xv.y * b4.y + xv.z * b4.z + xv.w * b4.w;
        acc.z += xv.x * c4.x + xv.y * c4.y + xv.z * c4.z + xv.w * c4.w;
        acc.w += xv.x * d4.x + xv.y * d4.y + xv.z * d4.z + xv.w * d4.w;
    }
    size_t gb = (size_t)(base + node) * D_HID;
    g[gb + og     ] = acc.x;
    g[gb + og +  8] = acc.y;
    g[gb + og + 16] = acc.z;
    g[gb + og + 24] = acc.w;
}

// ---------------- pull hop ----------------
// out[c] = dis[c]^2*h[c] + sum_e norm_e * h[src_e];  32 lanes per node, lane = dim

__global__ __launch_bounds__(256) void k_pull(const int* __restrict__ start,
                                              const u32* __restrict__ csr,
                                              const float* __restrict__ dis,
                                              const float* __restrict__ h,
                                              float* __restrict__ out) {
    int g    = blockIdx.x * 8 + (threadIdx.x >> 5);
    int lane = threadIdx.x & 31;
    if (g >= N_NODES) return;

    int s = start[g];
    int e = start[g + 1];
    float ds  = dis[g];
    float acc = ds * ds * h[(size_t)g * D_HID + lane];

    for (int base = s; base < e; base += 32) {
        int idx = base + lane;
        u32 p = (idx < e) ? csr[idx] : 0u;   // pad: src=0, norm=0
        int rem = e - base;
        for (int jj = 0; jj < 32; jj += 8) {
            if (jj >= rem) break;
#pragma unroll
            for (int j = 0; j < 8; ++j) {
                u32 pj = __shfl(p, jj + j, 32);
                float nv = (float)(pj & 32767u) * (1.0f / 32768.0f);
                int src = (int)(pj >> 15);
                acc += nv * h[(size_t)src * D_HID + lane];
            }
        }
    }
    out[(size_t)g * D_HID + lane] = acc;
}

// ---------------- epilogue: bias + ELU + FC + log_softmax ----------------

__global__ __launch_bounds__(256) void k_final(const float* __restrict__ h,
                                               const float* __restrict__ bc,
                                               const float* __restrict__ Wfc,
                                               const float* __restrict__ bf,
                                               float* __restrict__ out) {
    __shared__ float wf[N_CLS * D_HID];
    __shared__ float bcs[D_HID];
    __shared__ float bfs[N_CLS];
    const int tid = threadIdx.x;
    for (int i = tid; i < N_CLS * D_HID; i += 256) wf[i] = Wfc[i];
    if (tid < D_HID) bcs[tid] = bc[tid];
    if (tid < N_CLS) bfs[tid] = bf[tid];
    __syncthreads();

    int node = blockIdx.x * 256 + tid;
    if (node >= N_NODES) return;

    float a[D_HID];
    const float4* hp = reinterpret_cast<const float4*>(h + (size_t)node * D_HID);
#pragma unroll
    for (int j = 0; j < 8; ++j) {
        float4 v = hp[j];
        float z0 = v.x + bcs[j * 4 + 0];
        float z1 = v.y + bcs[j * 4 + 1];
        float z2 = v.z + bcs[j * 4 + 2];
        float z3 = v.w + bcs[j * 4 + 3];
        a[j * 4 + 0] = z0 > 0.f ? z0 : expm1f(z0);
        a[j * 4 + 1] = z1 > 0.f ? z1 : expm1f(z1);
        a[j * 4 + 2] = z2 > 0.f ? z2 : expm1f(z2);
        a[j * 4 + 3] = z3 > 0.f ? z3 : expm1f(z3);
    }

    float logits[N_CLS];
    float m = -1e30f;
#pragma unroll
    for (int c = 0; c < N_CLS; ++c) {
        float accv = bfs[c];
        const float* wr = &wf[c * D_HID];
#pragma unroll
        for (int o = 0; o < D_HID; ++o) accv += a[o] * wr[o];
        logits[c] = accv;
        m = fmaxf(m, accv);
    }
    float s = 0.f;
#pragma unroll
    for (int c = 0; c < N_CLS; ++c) s += expf(logits[c] - m);
    float lse = m + logf(s);
    float* op = out + (size_t)node * N_CLS;
#pragma unroll
    for (int c = 0; c < N_CLS; ++c) op[c] = logits[c] - lse;
}

// ---------------- launch ----------------

extern "C" void kernel_launch(void* const* d_in, const int* in_sizes, int n_in,
                              void* d_out, int out_size, void* d_ws, size_t ws_size,
                              hipStream_t stream) {
    const float* x   = (const float*)d_in[0];
    const int*   ei  = (const int*)d_in[1];
    const float* ea  = (const float*)d_in[2];
    const float* Wc  = (const float*)d_in[3];
    const float* bc  = (const float*)d_in[4];
    const float* Wfc = (const float*)d_in[5];
    const float* bf  = (const float*)d_in[6];
    float* out = (float*)d_out;
    float* ws  = (float*)d_ws;

    const int* row = ei;             // edge_index[0]
    const int* col = ei + N_EDGES;   // edge_index[1]

    // workspace layout (float-element offsets; base is 256B aligned)
    u64*   packed = (u64*)ws;                            // 100000 u64  [0, 200000)
    float* dis    = ws + 200000;                         // 100000
    int*   inc    = (int*)(ws + 300000);                 // 100000
    int*   part   = (int*)(ws + 400000);                 // 128
    int*   pexcl  = (int*)(ws + 400128);                 // 128
    int*   startp = (int*)(ws + 400256);                 // 100001
    int*   cursor = (int*)(ws + 500260);                 // 100000
    u32*   csr    = (u32*)(ws + 600260);                 // 3.2M u32
    float* bufA   = ws + 3800260;                        // 3.2M
    float* bufB   = ws + 7000260;                        // 3.2M
    // total 10,200,260 floats = 40.8 MB

    const int GN = (N_NODES + 255) / 256;    // 391
    const int GE = (N_EDGES + 255) / 256;    // 12500
    const int GP = (N_NODES + 7) / 8;        // 12500

    hipMemsetAsync(packed, 0, (size_t)N_NODES * sizeof(u64), stream);
    k_count <<<GE, 256, 0, stream>>>(col, ea, packed);

    k_scan1 <<<N_SCAN_BLKS, SCAN_BLK, 0, stream>>>(packed, dis, inc, part);
    k_scan2 <<<1, 128, 0, stream>>>(part, pexcl);
    k_scan3 <<<GN, 256, 0, stream>>>(inc, pexcl, startp, cursor);
    k_fill  <<<GE, 256, 0, stream>>>(row, col, ea, dis, cursor, csr);

    k_gemm1 <<<N_NODES / 32, 256, 0, stream>>>(x, Wc, bufA);

    k_pull  <<<GP, 256, 0, stream>>>(startp, csr, dis, bufA, bufB);
    k_pull  <<<GP, 256, 0, stream>>>(startp, csr, dis, bufB, bufA);
    k_pull  <<<GP, 256, 0, stream>>>(startp, csr, dis, bufA, bufB);

    k_final <<<GN, 256, 0, stream>>>(bufB, bc, Wfc, bf, out);
}

// Round 4
// 562.993 us; speedup vs baseline: 2.5896x; 1.4334x over previous
//
#include <hip/hip_runtime.h>
#include <math.h>

#define N_NODES 100000
#define N_EDGES 3200000
#define D_IN    256
#define D_HID   32
#define N_CLS   40

#define NCOARSE 3125      // coarse buckets of 32 nodes (100000 = 3125*32)
#define NB_A    256
#define CHUNK_A 12500     // 256*12500 = 3.2M
#define NB_C    256
#define CHUNK_C 12500

typedef unsigned int u32;
typedef unsigned short u16;
typedef unsigned long long u64;

__device__ __forceinline__ float bf2f(u16 v) {
    return __uint_as_float(((u32)v) << 16);
}
__device__ __forceinline__ u16 f2bf(float f) {
    u32 u = __float_as_uint(f);
    u32 r = u + 0x7FFFu + ((u >> 16) & 1u);   // round-to-nearest-even
    return (u16)(r >> 16);
}

// ---------------- A: coarse histogram (LDS-aggregated) ----------------

__global__ __launch_bounds__(256) void k_hist(const int* __restrict__ col,
                                              int* __restrict__ chist) {
    __shared__ u32 h[NCOARSE];
    for (int j = threadIdx.x; j < NCOARSE; j += 256) h[j] = 0;
    __syncthreads();
    int s = blockIdx.x * CHUNK_A;
    for (int i = s + threadIdx.x; i < s + CHUNK_A; i += 256)
        atomicAdd(&h[((u32)col[i]) >> 5], 1u);
    __syncthreads();
    for (int j = threadIdx.x; j < NCOARSE; j += 256) {
        u32 c = h[j];
        if (c) atomicAdd((u32*)&chist[j], c);
    }
}

// ---------------- B: scan coarse counts (single block) ----------------

__global__ __launch_bounds__(1024) void k_scanc(const int* __restrict__ chist,
                                                int* __restrict__ cstart,
                                                int* __restrict__ ccur) {
    __shared__ int ts[1024];
    int t = threadIdx.x;
    int idx = t * 4;
    int v0 = (idx     < NCOARSE) ? chist[idx]     : 0;
    int v1 = (idx + 1 < NCOARSE) ? chist[idx + 1] : 0;
    int v2 = (idx + 2 < NCOARSE) ? chist[idx + 2] : 0;
    int v3 = (idx + 3 < NCOARSE) ? chist[idx + 3] : 0;
    int s = v0 + v1 + v2 + v3;
    ts[t] = s;
    __syncthreads();
    for (int off = 1; off < 1024; off <<= 1) {
        int u = (t >= off) ? ts[t - off] : 0;
        __syncthreads();
        ts[t] += u;
        __syncthreads();
    }
    int run = ts[t] - s;   // exclusive prefix
    if (idx < NCOARSE)     { cstart[idx]     = run; ccur[idx]     = run; run += v0; }
    if (idx + 1 < NCOARSE) { cstart[idx + 1] = run; ccur[idx + 1] = run; run += v1; }
    if (idx + 2 < NCOARSE) { cstart[idx + 2] = run; ccur[idx + 2] = run; run += v2; }
    if (idx + 3 < NCOARSE) { cstart[idx + 3] = run; ccur[idx + 3] = run; run += v3; }
    if (t == 1023) cstart[NCOARSE] = ts[t];
}

// ---------------- C: coarse scatter (per-block range reservation) ----------------
// entry: key = (fine5 << 17) | src17 ; payload = w bits

__global__ __launch_bounds__(256) void k_coarse(const int* __restrict__ row,
                                                const int* __restrict__ col,
                                                const float* __restrict__ w,
                                                int* __restrict__ ccur,
                                                uint2* __restrict__ coarse) {
    __shared__ u32 lcnt[NCOARSE];
    __shared__ u32 lbase[NCOARSE];
    for (int j = threadIdx.x; j < NCOARSE; j += 256) lcnt[j] = 0;
    __syncthreads();
    int s = blockIdx.x * CHUNK_C;
    for (int i = s + threadIdx.x; i < s + CHUNK_C; i += 256)
        atomicAdd(&lcnt[((u32)col[i]) >> 5], 1u);
    __syncthreads();
    for (int j = threadIdx.x; j < NCOARSE; j += 256) {
        u32 c = lcnt[j];
        lbase[j] = c ? atomicAdd((u32*)&ccur[j], c) : 0u;
    }
    __syncthreads();
    for (int i = s + threadIdx.x; i < s + CHUNK_C; i += 256) {
        u32 c = (u32)col[i];
        u32 b = c >> 5;
        u32 pos = atomicAdd(&lbase[b], 1u);
        u32 key = ((c & 31u) << 17) | (u32)row[i];
        coarse[pos] = make_uint2(key, __float_as_uint(w[i]));
    }
}

// ---------------- D1: per-bucket weighted degree -> dis; node start offsets ----------------

__global__ __launch_bounds__(256) void k_deg(const uint2* __restrict__ coarse,
                                             const int* __restrict__ cstart,
                                             float* __restrict__ dis,
                                             int* __restrict__ startp) {
    __shared__ u32 c32[32];
    __shared__ float ws32[32];
    int b = blockIdx.x;
    int s = cstart[b], e = cstart[b + 1];
    if (threadIdx.x < 32) { c32[threadIdx.x] = 0; ws32[threadIdx.x] = 0.f; }
    __syncthreads();
    for (int i = s + threadIdx.x; i < e; i += 256) {
        uint2 p = coarse[i];
        u32 f = (p.x >> 17) & 31u;
        atomicAdd(&c32[f], 1u);
        atomicAdd(&ws32[f], __uint_as_float(p.y));
    }
    __syncthreads();
    if (threadIdx.x < 32) {
        int node = b * 32 + threadIdx.x;
        dis[node] = rsqrtf(1.0f + ws32[threadIdx.x]);
    }
    if (threadIdx.x == 0) {
        int run = s;
        for (int f = 0; f < 32; ++f) { startp[b * 32 + f] = run; run += (int)c32[f]; }
        if (b == NCOARSE - 1) startp[N_NODES] = run;
    }
}

// ---------------- D2: fine sort within bucket -> final CSR (src<<15 | m15), m = dis[src]*w ----------------

__global__ __launch_bounds__(256) void k_fine(const uint2* __restrict__ coarse,
                                              const int* __restrict__ cstart,
                                              const int* __restrict__ startp,
                                              const float* __restrict__ dis,
                                              u32* __restrict__ csr) {
    __shared__ u32 cur[32];
    int b = blockIdx.x;
    int s = cstart[b], e = cstart[b + 1];
    if (threadIdx.x < 32) cur[threadIdx.x] = (u32)startp[b * 32 + threadIdx.x];
    __syncthreads();
    for (int i = s + threadIdx.x; i < e; i += 256) {
        uint2 p = coarse[i];
        u32 f = (p.x >> 17) & 31u;
        u32 r = p.x & 0x1FFFFu;
        float m = dis[r] * __uint_as_float(p.y);   // < 1.0
        u32 q = (u32)(m * 32768.0f + 0.5f);
        if (q > 32767u) q = 32767u;
        u32 pos = atomicAdd(&cur[f], 1u);
        csr[pos] = (r << 15) | q;
    }
}

// ---------------- GEMM1: g = x @ Wc^T  (100000x256 @ 256x32), bf16 out ----------------

#define LSTRIDE 260

__global__ __launch_bounds__(256) void k_gemm1(const float* __restrict__ x,
                                               const float* __restrict__ Wc,
                                               u16* __restrict__ g) {
    __shared__ float xs[32 * LSTRIDE];
    __shared__ float wsl[32 * LSTRIDE];
    const int tid  = threadIdx.x;
    const int base = blockIdx.x * 32;

    for (int i = tid; i < 2048; i += 256) {
        int r = i >> 6, j = i & 63;
        float4 v = reinterpret_cast<const float4*>(x)[(size_t)(base + r) * 64 + j];
        *reinterpret_cast<float4*>(&xs[r * LSTRIDE + j * 4]) = v;
    }
    for (int i = tid; i < 2048; i += 256) {
        int r = i >> 6, j = i & 63;
        float4 v = reinterpret_cast<const float4*>(Wc)[i];
        *reinterpret_cast<float4*>(&wsl[r * LSTRIDE + j * 4]) = v;
    }
    __syncthreads();

    const int node = tid >> 3;
    const int og   = tid & 7;
    float4 acc = make_float4(0.f, 0.f, 0.f, 0.f);
    const float* xrow = &xs[node * LSTRIDE];
    const float* w0 = &wsl[(og     ) * LSTRIDE];
    const float* w1 = &wsl[(og +  8) * LSTRIDE];
    const float* w2 = &wsl[(og + 16) * LSTRIDE];
    const float* w3 = &wsl[(og + 24) * LSTRIDE];

#pragma unroll 4
    for (int k = 0; k < 256; k += 4) {
        float4 xv = *reinterpret_cast<const float4*>(&xrow[k]);
        float4 a4 = *reinterpret_cast<const float4*>(&w0[k]);
        float4 b4 = *reinterpret_cast<const float4*>(&w1[k]);
        float4 c4 = *reinterpret_cast<const float4*>(&w2[k]);
        float4 d4 = *reinterpret_cast<const float4*>(&w3[k]);
        acc.x += xv.x * a4.x + xv.y * a4.y + xv.z * a4.z + xv.w * a4.w;
        acc.y += xv.x * b4.x + xv.y * b4.y + xv.z * b4.z + xv.w * b4.w;
        acc.z += xv.x * c4.x + xv.y * c4.y + xv.z * c4.z + xv.w * c4.w;
        acc.w += xv.x * d4.x + xv.y * d4.y + xv.z * d4.z + xv.w * d4.w;
    }
    size_t gb = (size_t)(base + node) * D_HID;
    g[gb + og     ] = f2bf(acc.x);
    g[gb + og +  8] = f2bf(acc.y);
    g[gb + og + 16] = f2bf(acc.z);
    g[gb + og + 24] = f2bf(acc.w);
}

// ---------------- pull hop (bf16 h): out[c] = dis[c]*(dis[c]*h[c] + sum m_e*h[src]) ----------------

__global__ __launch_bounds__(256) void k_pull(const int* __restrict__ start,
                                              const u32* __restrict__ csr,
                                              const float* __restrict__ dis,
                                              const u16* __restrict__ h,
                                              u16* __restrict__ out) {
    int g    = blockIdx.x * 8 + (threadIdx.x >> 5);
    int lane = threadIdx.x & 31;
    if (g >= N_NODES) return;

    int s = start[g];
    int e = start[g + 1];
    float ds  = dis[g];
    float acc = ds * bf2f(h[(size_t)g * D_HID + lane]);

    for (int base = s; base < e; base += 32) {
        int idx = base + lane;
        u32 p = (idx < e) ? csr[idx] : 0u;   // pad: src=0, m=0
        int rem = e - base;
        for (int jj = 0; jj < 32; jj += 8) {
            if (jj >= rem) break;
#pragma unroll
            for (int j = 0; j < 8; ++j) {
                u32 pj = __shfl(p, jj + j, 32);
                float nv = (float)(pj & 32767u) * (1.0f / 32768.0f);
                u32 src = pj >> 15;
                acc += nv * bf2f(h[(size_t)src * D_HID + lane]);
            }
        }
    }
    out[(size_t)g * D_HID + lane] = f2bf(ds * acc);
}

// ---------------- epilogue: bias + ELU + FC + log_softmax ----------------

__global__ __launch_bounds__(256) void k_final(const u16* __restrict__ h,
                                               const float* __restrict__ bc,
                                               const float* __restrict__ Wfc,
                                               const float* __restrict__ bf,
                                               float* __restrict__ out) {
    __shared__ float wf[N_CLS * D_HID];
    __shared__ float bcs[D_HID];
    __shared__ float bfs[N_CLS];
    const int tid = threadIdx.x;
    for (int i = tid; i < N_CLS * D_HID; i += 256) wf[i] = Wfc[i];
    if (tid < D_HID) bcs[tid] = bc[tid];
    if (tid < N_CLS) bfs[tid] = bf[tid];
    __syncthreads();

    int node = blockIdx.x * 256 + tid;
    if (node >= N_NODES) return;

    float a[D_HID];
    const u32* hp = reinterpret_cast<const u32*>(h + (size_t)node * D_HID);
#pragma unroll
    for (int j = 0; j < 16; ++j) {
        u32 v = hp[j];
        float z0 = bf2f((u16)(v & 0xFFFFu)) + bcs[j * 2 + 0];
        float z1 = bf2f((u16)(v >> 16))     + bcs[j * 2 + 1];
        a[j * 2 + 0] = z0 > 0.f ? z0 : expm1f(z0);
        a[j * 2 + 1] = z1 > 0.f ? z1 : expm1f(z1);
    }

    float logits[N_CLS];
    float m = -1e30f;
#pragma unroll
    for (int c = 0; c < N_CLS; ++c) {
        float accv = bfs[c];
        const float* wr = &wf[c * D_HID];
#pragma unroll
        for (int o = 0; o < D_HID; ++o) accv += a[o] * wr[o];
        logits[c] = accv;
        m = fmaxf(m, accv);
    }
    float sum = 0.f;
#pragma unroll
    for (int c = 0; c < N_CLS; ++c) sum += expf(logits[c] - m);
    float lse = m + logf(sum);
    float* op = out + (size_t)node * N_CLS;
#pragma unroll
    for (int c = 0; c < N_CLS; ++c) op[c] = logits[c] - lse;
}

// ---------------- launch ----------------

extern "C" void kernel_launch(void* const* d_in, const int* in_sizes, int n_in,
                              void* d_out, int out_size, void* d_ws, size_t ws_size,
                              hipStream_t stream) {
    const float* x   = (const float*)d_in[0];
    const int*   ei  = (const int*)d_in[1];
    const float* ea  = (const float*)d_in[2];
    const float* Wc  = (const float*)d_in[3];
    const float* bc  = (const float*)d_in[4];
    const float* Wfc = (const float*)d_in[5];
    const float* bf  = (const float*)d_in[6];
    float* out = (float*)d_out;
    float* ws  = (float*)d_ws;

    const int* row = ei;             // edge_index[0]
    const int* col = ei + N_EDGES;   // edge_index[1]

    // workspace layout (float-element offsets; all 16B-aligned)
    float* dis    = ws;                          // 100000
    int*   chist  = (int*)(ws + 100000);         // 3125  -> pad 103128
    int*   ccur   = (int*)(ws + 103128);         // 3125  -> pad 106256
    int*   cstart = (int*)(ws + 106256);         // 3126  -> pad 109384
    int*   startp = (int*)(ws + 109384);         // 100001-> pad 209388
    uint2* coarse = (uint2*)(ws + 209388);       // 3.2M uint2 = 6.4M elems
    u32*   csr    = (u32*)(ws + 6609388);        // 3.2M u32
    u16*   bufA   = (u16*)(ws + 9809388);        // 3.2M u16 = 1.6M elems
    u16*   bufB   = (u16*)(ws + 11409388);       // 3.2M u16
    // total 13,009,388 floats = 52.0 MB

    const int GN = (N_NODES + 255) / 256;    // 391
    const int GP = (N_NODES + 7) / 8;        // 12500

    hipMemsetAsync(chist, 0, NCOARSE * sizeof(int), stream);
    k_hist  <<<NB_A, 256, 0, stream>>>(col, chist);
    k_scanc <<<1, 1024, 0, stream>>>(chist, cstart, ccur);
    k_coarse<<<NB_C, 256, 0, stream>>>(row, col, ea, ccur, coarse);
    k_deg   <<<NCOARSE, 256, 0, stream>>>(coarse, cstart, dis, startp);
    k_fine  <<<NCOARSE, 256, 0, stream>>>(coarse, cstart, startp, dis, csr);

    k_gemm1 <<<N_NODES / 32, 256, 0, stream>>>(x, Wc, bufA);

    k_pull  <<<GP, 256, 0, stream>>>(startp, csr, dis, bufA, bufB);
    k_pull  <<<GP, 256, 0, stream>>>(startp, csr, dis, bufB, bufA);
    k_pull  <<<GP, 256, 0, stream>>>(startp, csr, dis, bufA, bufB);

    k_final <<<GN, 256, 0, stream>>>(bufB, bc, Wfc, bf, out);
}